// Round 1
// baseline (70.455 us; speedup 1.0000x reference)
//
#include <hip/hip_runtime.h>

#define NB 10

__global__ __launch_bounds__(256) void ece_partial_kernel(
    const float* __restrict__ conf, const float* __restrict__ corr,
    float* __restrict__ ws, int n)
{
    float acc[NB];
#pragma unroll
    for (int j = 0; j < NB; ++j) acc[j] = 0.0f;

    const int tid = threadIdx.x;
    const int gid = blockIdx.x * blockDim.x + tid;
    const int stride = gridDim.x * blockDim.x;
    const int n4 = n >> 2;

    const float4* __restrict__ c4 = reinterpret_cast<const float4*>(conf);
    const float4* __restrict__ k4 = reinterpret_cast<const float4*>(corr);

    for (int i = gid; i < n4; i += stride) {
        const float4 c = c4[i];
        const float4 k = k4[i];
        const float cs[4] = {c.x, c.y, c.z, c.w};
        const float ks[4] = {k.x, k.y, k.z, k.w};
#pragma unroll
        for (int e = 0; e < 4; ++e) {
            const int idx = (int)(cs[e] * (float)NB);  // conf >= 0, trunc == floor
            const float d = cs[e] - ks[e];
#pragma unroll
            for (int j = 0; j < NB; ++j)
                acc[j] += (idx == j) ? d : 0.0f;  // idx>=10 (ref overflow bin) dropped
        }
    }

    // tail if n not a multiple of 4 (not the case for B=2^25, but be correct)
    if (gid == 0) {
        for (int i = n4 << 2; i < n; ++i) {
            const float cv = conf[i];
            const int idx = (int)(cv * (float)NB);
            const float d = cv - corr[i];
#pragma unroll
            for (int j = 0; j < NB; ++j)
                acc[j] += (idx == j) ? d : 0.0f;
        }
    }

    // block reduction: [bin][tid] layout -> bank = tid%32, conflict-free
    __shared__ float red[NB][256];
#pragma unroll
    for (int j = 0; j < NB; ++j) red[j][tid] = acc[j];
    __syncthreads();

    for (int s = 128; s > 0; s >>= 1) {
        if (tid < s) {
#pragma unroll
            for (int j = 0; j < NB; ++j) red[j][tid] += red[j][tid + s];
        }
        __syncthreads();
    }

    if (tid < NB) atomicAdd(&ws[tid], red[tid][0]);
}

__global__ void ece_final_kernel(const float* __restrict__ ws,
                                 float* __restrict__ out, int n)
{
    if (threadIdx.x == 0 && blockIdx.x == 0) {
        float s = 0.0f;
#pragma unroll
        for (int j = 0; j < NB; ++j) s += fabsf(ws[j]);
        out[0] = s / (float)n;
    }
}

extern "C" void kernel_launch(void* const* d_in, const int* in_sizes, int n_in,
                              void* d_out, int out_size, void* d_ws, size_t ws_size,
                              hipStream_t stream) {
    const float* conf = (const float*)d_in[0];
    const float* corr = (const float*)d_in[1];
    float* ws = (float*)d_ws;
    float* out = (float*)d_out;
    const int n = in_sizes[0];

    hipMemsetAsync(ws, 0, NB * sizeof(float), stream);

    const int n4 = n >> 2;
    int blocks = (n4 + 255) / 256;
    if (blocks > 2048) blocks = 2048;
    if (blocks < 1) blocks = 1;

    ece_partial_kernel<<<blocks, 256, 0, stream>>>(conf, corr, ws, n);
    ece_final_kernel<<<1, 64, 0, stream>>>(ws, out, n);
}

// Round 2
// 64.065 us; speedup vs baseline: 1.0998x; 1.0998x over previous
//
#include <hip/hip_runtime.h>

#define NB 10
#define UNROLL 4

__global__ __launch_bounds__(256) void ece_partial_kernel(
    const float* __restrict__ conf, const float* __restrict__ corr,
    float* __restrict__ ws, int n)
{
    float acc[NB];
#pragma unroll
    for (int j = 0; j < NB; ++j) acc[j] = 0.0f;

    const int tid = threadIdx.x;
    const int gid = blockIdx.x * blockDim.x + tid;
    const int stride = gridDim.x * blockDim.x;
    const int n4 = n >> 2;

    const float4* __restrict__ c4 = reinterpret_cast<const float4*>(conf);
    const float4* __restrict__ k4 = reinterpret_cast<const float4*>(corr);

    int i = gid;
    const int big_stride = stride * UNROLL;

    // Unrolled main loop: 8 independent float4 loads in flight (128B/lane)
    // before any dependent compute -> covers L3/HBM latency with MLP.
    for (; i + (UNROLL - 1) * stride < n4; i += big_stride) {
        float4 c[UNROLL], k[UNROLL];
#pragma unroll
        for (int u = 0; u < UNROLL; ++u) {
            c[u] = c4[i + u * stride];
            k[u] = k4[i + u * stride];
        }
#pragma unroll
        for (int u = 0; u < UNROLL; ++u) {
            const float cs[4] = {c[u].x, c[u].y, c[u].z, c[u].w};
            const float ks[4] = {k[u].x, k[u].y, k[u].z, k[u].w};
#pragma unroll
            for (int e = 0; e < 4; ++e) {
                const int idx = (int)(cs[e] * (float)NB);  // conf >= 0: trunc == floor
                const float d = cs[e] - ks[e];
#pragma unroll
                for (int j = 0; j < NB; ++j)
                    acc[j] += (idx == j) ? d : 0.0f;  // idx>=10 (overflow bin) dropped
            }
        }
    }

    // remainder grid-stride iterations
    for (; i < n4; i += stride) {
        const float4 c = c4[i];
        const float4 k = k4[i];
        const float cs[4] = {c.x, c.y, c.z, c.w};
        const float ks[4] = {k.x, k.y, k.z, k.w};
#pragma unroll
        for (int e = 0; e < 4; ++e) {
            const int idx = (int)(cs[e] * (float)NB);
            const float d = cs[e] - ks[e];
#pragma unroll
            for (int j = 0; j < NB; ++j)
                acc[j] += (idx == j) ? d : 0.0f;
        }
    }

    // scalar tail if n not a multiple of 4
    if (gid == 0) {
        for (int t = n4 << 2; t < n; ++t) {
            const float cv = conf[t];
            const int idx = (int)(cv * (float)NB);
            const float d = cv - corr[t];
#pragma unroll
            for (int j = 0; j < NB; ++j)
                acc[j] += (idx == j) ? d : 0.0f;
        }
    }

    // block reduction: [bin][tid] layout -> bank = tid%32, conflict-free
    __shared__ float red[NB][256];
#pragma unroll
    for (int j = 0; j < NB; ++j) red[j][tid] = acc[j];
    __syncthreads();

    for (int s = 128; s > 0; s >>= 1) {
        if (tid < s) {
#pragma unroll
            for (int j = 0; j < NB; ++j) red[j][tid] += red[j][tid + s];
        }
        __syncthreads();
    }

    if (tid < NB) atomicAdd(&ws[tid], red[tid][0]);
}

__global__ void ece_final_kernel(const float* __restrict__ ws,
                                 float* __restrict__ out, int n)
{
    if (threadIdx.x == 0 && blockIdx.x == 0) {
        float s = 0.0f;
#pragma unroll
        for (int j = 0; j < NB; ++j) s += fabsf(ws[j]);
        out[0] = s / (float)n;
    }
}

extern "C" void kernel_launch(void* const* d_in, const int* in_sizes, int n_in,
                              void* d_out, int out_size, void* d_ws, size_t ws_size,
                              hipStream_t stream) {
    const float* conf = (const float*)d_in[0];
    const float* corr = (const float*)d_in[1];
    float* ws = (float*)d_ws;
    float* out = (float*)d_out;
    const int n = in_sizes[0];

    hipMemsetAsync(ws, 0, NB * sizeof(float), stream);

    const int n4 = n >> 2;
    int blocks = (n4 + 255) / 256;
    if (blocks > 2048) blocks = 2048;
    if (blocks < 1) blocks = 1;

    ece_partial_kernel<<<blocks, 256, 0, stream>>>(conf, corr, ws, n);
    ece_final_kernel<<<1, 64, 0, stream>>>(ws, out, n);
}

// Round 3
// 64.018 us; speedup vs baseline: 1.1006x; 1.0007x over previous
//
#include <hip/hip_runtime.h>

#define NB 10

typedef float f32x4 __attribute__((ext_vector_type(4)));

// Volatile asm load: cannot be sunk next to its use by the scheduler, so the
// issued loads genuinely stay in flight (the R2 compiler re-serialized plain
// unrolled loads to save VGPRs -> zero MLP gain).
__device__ __forceinline__ f32x4 async_load(const float* p) {
    f32x4 r;
    asm volatile("global_load_dwordx4 %0, %1, off"
                 : "=v"(r)
                 : "v"(p)
                 : "memory");
    return r;
}

__device__ __forceinline__ void accum_pair(const f32x4 c, const f32x4 k,
                                           float acc[NB]) {
#pragma unroll
    for (int e = 0; e < 4; ++e) {
        const int idx = (int)(c[e] * (float)NB);  // conf >= 0: trunc == floor
        const float d = c[e] - k[e];
#pragma unroll
        for (int j = 0; j < NB; ++j)
            acc[j] += (idx == j) ? d : 0.0f;  // idx>=10 (overflow bin) dropped
    }
}

__global__ __launch_bounds__(256) void ece_partial_kernel(
    const float* __restrict__ conf, const float* __restrict__ corr,
    float* __restrict__ ws, int n)
{
    float acc[NB];
#pragma unroll
    for (int j = 0; j < NB; ++j) acc[j] = 0.0f;

    const int tid = threadIdx.x;
    const int gid = blockIdx.x * blockDim.x + tid;
    const int stride = gridDim.x * blockDim.x;  // in float4 units
    const int n4 = n >> 2;

    int i = gid;

    // Main loop: 8 forced-in-flight dwordx4 loads (8 KB/lane-pair-group),
    // counted waits so compute overlaps the remaining outstanding loads.
    for (; i + 3 * stride < n4; i += 4 * stride) {
        const float* cb = conf + 4ll * i;
        const float* kb = corr + 4ll * i;
        const long long soff = 4ll * stride;

        f32x4 c0 = async_load(cb);
        f32x4 k0 = async_load(kb);
        f32x4 c1 = async_load(cb + soff);
        f32x4 k1 = async_load(kb + soff);
        f32x4 c2 = async_load(cb + 2 * soff);
        f32x4 k2 = async_load(kb + 2 * soff);
        f32x4 c3 = async_load(cb + 3 * soff);
        f32x4 k3 = async_load(kb + 3 * soff);

        asm volatile("s_waitcnt vmcnt(4)" ::: "memory");
        __builtin_amdgcn_sched_barrier(0);
        accum_pair(c0, k0, acc);
        accum_pair(c1, k1, acc);

        asm volatile("s_waitcnt vmcnt(0)" ::: "memory");
        __builtin_amdgcn_sched_barrier(0);
        accum_pair(c2, k2, acc);
        accum_pair(c3, k3, acc);
    }

    // remainder grid-stride iterations (plain loads; compiler inserts waits)
    for (; i < n4; i += stride) {
        const f32x4 c = *reinterpret_cast<const f32x4*>(conf + 4ll * i);
        const f32x4 k = *reinterpret_cast<const f32x4*>(corr + 4ll * i);
        accum_pair(c, k, acc);
    }

    // scalar tail if n not a multiple of 4
    if (gid == 0) {
        for (int t = (n4 << 2); t < n; ++t) {
            const float cv = conf[t];
            const int idx = (int)(cv * (float)NB);
            const float d = cv - corr[t];
#pragma unroll
            for (int j = 0; j < NB; ++j)
                acc[j] += (idx == j) ? d : 0.0f;
        }
    }

    // block reduction: [bin][tid] layout -> bank = tid%32, conflict-free
    __shared__ float red[NB][256];
#pragma unroll
    for (int j = 0; j < NB; ++j) red[j][tid] = acc[j];
    __syncthreads();

    for (int s = 128; s > 0; s >>= 1) {
        if (tid < s) {
#pragma unroll
            for (int j = 0; j < NB; ++j) red[j][tid] += red[j][tid + s];
        }
        __syncthreads();
    }

    if (tid < NB) atomicAdd(&ws[tid], red[tid][0]);
}

__global__ void ece_final_kernel(const float* __restrict__ ws,
                                 float* __restrict__ out, int n)
{
    if (threadIdx.x == 0 && blockIdx.x == 0) {
        float s = 0.0f;
#pragma unroll
        for (int j = 0; j < NB; ++j) s += fabsf(ws[j]);
        out[0] = s / (float)n;
    }
}

extern "C" void kernel_launch(void* const* d_in, const int* in_sizes, int n_in,
                              void* d_out, int out_size, void* d_ws, size_t ws_size,
                              hipStream_t stream) {
    const float* conf = (const float*)d_in[0];
    const float* corr = (const float*)d_in[1];
    float* ws = (float*)d_ws;
    float* out = (float*)d_out;
    const int n = in_sizes[0];

    hipMemsetAsync(ws, 0, NB * sizeof(float), stream);

    const int n4 = n >> 2;
    int blocks = (n4 + 255) / 256;
    if (blocks > 2048) blocks = 2048;
    if (blocks < 1) blocks = 1;

    ece_partial_kernel<<<blocks, 256, 0, stream>>>(conf, corr, ws, n);
    ece_final_kernel<<<1, 64, 0, stream>>>(ws, out, n);
}

// Round 4
// 55.185 us; speedup vs baseline: 1.2767x; 1.1601x over previous
//
#include <hip/hip_runtime.h>

#define NB 10

typedef float f32x4 __attribute__((ext_vector_type(4)));

// Volatile asm load: cannot be sunk next to its use by the scheduler, so the
// issued loads genuinely stay in flight.
__device__ __forceinline__ f32x4 async_load(const float* p) {
    f32x4 r;
    asm volatile("global_load_dwordx4 %0, %1, off"
                 : "=v"(r)
                 : "v"(p)
                 : "memory");
    return r;
}

__device__ __forceinline__ void accum_pair(const f32x4 c, const f32x4 k,
                                           float acc[NB]) {
#pragma unroll
    for (int e = 0; e < 4; ++e) {
        const int idx = (int)(c[e] * (float)NB);  // conf >= 0: trunc == floor
        const float d = c[e] - k[e];
#pragma unroll
        for (int j = 0; j < NB; ++j)
            acc[j] += (idx == j) ? d : 0.0f;  // idx>=10 (overflow bin) dropped
    }
}

// Stage 1: per-block bin sums of (conf - correct), written with plain stores.
// NO global atomics: 2048 blocks x 10 bins of atomicAdd to one 64B line was a
// serialized coherence-point tail (~15 us theory) since uniform blocks all
// finish together.
__global__ __launch_bounds__(256) void ece_partial_kernel(
    const float* __restrict__ conf, const float* __restrict__ corr,
    float* __restrict__ ws, int n)
{
    float acc[NB];
#pragma unroll
    for (int j = 0; j < NB; ++j) acc[j] = 0.0f;

    const int tid = threadIdx.x;
    const int gid = blockIdx.x * blockDim.x + tid;
    const int stride = gridDim.x * blockDim.x;  // in float4 units
    const int n4 = n >> 2;

    int i = gid;

    for (; i + 3 * stride < n4; i += 4 * stride) {
        const float* cb = conf + 4ll * i;
        const float* kb = corr + 4ll * i;
        const long long soff = 4ll * stride;

        f32x4 c0 = async_load(cb);
        f32x4 k0 = async_load(kb);
        f32x4 c1 = async_load(cb + soff);
        f32x4 k1 = async_load(kb + soff);
        f32x4 c2 = async_load(cb + 2 * soff);
        f32x4 k2 = async_load(kb + 2 * soff);
        f32x4 c3 = async_load(cb + 3 * soff);
        f32x4 k3 = async_load(kb + 3 * soff);

        asm volatile("s_waitcnt vmcnt(4)" ::: "memory");
        __builtin_amdgcn_sched_barrier(0);
        accum_pair(c0, k0, acc);
        accum_pair(c1, k1, acc);

        asm volatile("s_waitcnt vmcnt(0)" ::: "memory");
        __builtin_amdgcn_sched_barrier(0);
        accum_pair(c2, k2, acc);
        accum_pair(c3, k3, acc);
    }

    for (; i < n4; i += stride) {
        const f32x4 c = *reinterpret_cast<const f32x4*>(conf + 4ll * i);
        const f32x4 k = *reinterpret_cast<const f32x4*>(corr + 4ll * i);
        accum_pair(c, k, acc);
    }

    if (gid == 0) {
        for (int t = (n4 << 2); t < n; ++t) {
            const float cv = conf[t];
            const int idx = (int)(cv * (float)NB);
            const float d = cv - corr[t];
#pragma unroll
            for (int j = 0; j < NB; ++j)
                acc[j] += (idx == j) ? d : 0.0f;
        }
    }

    // block reduction: [bin][tid] layout -> bank = tid%32, conflict-free
    __shared__ float red[NB][256];
#pragma unroll
    for (int j = 0; j < NB; ++j) red[j][tid] = acc[j];
    __syncthreads();

    for (int s = 128; s > 0; s >>= 1) {
        if (tid < s) {
#pragma unroll
            for (int j = 0; j < NB; ++j) red[j][tid] += red[j][tid + s];
        }
        __syncthreads();
    }

    // plain coalesced-ish stores: bin-major so stage 2 reads are coalesced
    if (tid < NB) ws[tid * gridDim.x + blockIdx.x] = red[tid][0];
}

// Stage 2: reduce nblk x NB partials, ece = sum_j |sum_b ws[j][b]| / n
__global__ __launch_bounds__(1024) void ece_final_kernel(
    const float* __restrict__ ws, float* __restrict__ out, int n, int nblk)
{
    const int tid = threadIdx.x;
    float acc[NB];
#pragma unroll
    for (int j = 0; j < NB; ++j) acc[j] = 0.0f;

    for (int i = tid; i < nblk; i += 1024) {
#pragma unroll
        for (int j = 0; j < NB; ++j) acc[j] += ws[j * nblk + i];
    }

    __shared__ float red[NB][1024];
#pragma unroll
    for (int j = 0; j < NB; ++j) red[j][tid] = acc[j];
    __syncthreads();

    for (int s = 512; s > 0; s >>= 1) {
        if (tid < s) {
#pragma unroll
            for (int j = 0; j < NB; ++j) red[j][tid] += red[j][tid + s];
        }
        __syncthreads();
    }

    if (tid == 0) {
        float s = 0.0f;
#pragma unroll
        for (int j = 0; j < NB; ++j) s += fabsf(red[j][0]);
        out[0] = s / (float)n;
    }
}

extern "C" void kernel_launch(void* const* d_in, const int* in_sizes, int n_in,
                              void* d_out, int out_size, void* d_ws, size_t ws_size,
                              hipStream_t stream) {
    const float* conf = (const float*)d_in[0];
    const float* corr = (const float*)d_in[1];
    float* ws = (float*)d_ws;
    float* out = (float*)d_out;
    const int n = in_sizes[0];

    const int n4 = n >> 2;
    int blocks = (n4 + 255) / 256;
    if (blocks > 2048) blocks = 2048;
    // safety: ws must hold blocks*NB floats
    const int maxblk = (int)(ws_size / (NB * sizeof(float)));
    if (blocks > maxblk) blocks = maxblk;
    if (blocks < 1) blocks = 1;

    ece_partial_kernel<<<blocks, 256, 0, stream>>>(conf, corr, ws, n);
    ece_final_kernel<<<1, 1024, 0, stream>>>(ws, out, n, blocks);
}